// Round 4
// baseline (358.603 us; speedup 1.0000x reference)
//
#include <hip/hip_runtime.h>

typedef __attribute__((ext_vector_type(8))) __bf16 bf16x8;
typedef __attribute__((ext_vector_type(4))) float floatx4;

#define WS_BIAS  131072   // 16384 f32 : 16*sigmoid(cpb) per [h][n][m]
#define WS_SCALE 196608   // 4 f32     : exp(min(logit_scale, log 100))
#define WS_TBL   196640   // 900 f32   : cpb table (225 x 4)

static __device__ __forceinline__ unsigned short f2bf_u(float f) {
  union { __bf16 b; unsigned short u; } cv; cv.b = (__bf16)f; return cv.u;
}
static __device__ __forceinline__ unsigned pkbf(float lo, float hi) {
  union { __bf16 b[2]; unsigned u; } cv; cv.b[0] = (__bf16)lo; cv.b[1] = (__bf16)hi; return cv.u;
}

// ---- prep: fp32 weights -> bf16 in ws; logit scale ----
__global__ void k_prep_weights(const float* __restrict__ qkv_w,
                               const float* __restrict__ proj_w,
                               const float* __restrict__ logit_scale,
                               unsigned short* __restrict__ wsQ,
                               float* __restrict__ wsScale)
{
  int t = blockIdx.x * 256 + threadIdx.x;   // 0..16383
  int i4 = t * 4;
  float4 v;
  if (i4 < 49152) v = *reinterpret_cast<const float4*>(qkv_w + i4);
  else            v = *reinterpret_cast<const float4*>(proj_w + (i4 - 49152));
  ushort4 pk;
  pk.x = f2bf_u(v.x); pk.y = f2bf_u(v.y); pk.z = f2bf_u(v.z); pk.w = f2bf_u(v.w);
  *reinterpret_cast<ushort4*>(wsQ + i4) = pk;
  if (t < 4) wsScale[t] = expf(fminf(logit_scale[t], 4.6051702f));
}

// ---- prep: CPB MLP table (225 x 4), one block per table row ----
__global__ void k_cpb_table(const float* __restrict__ w1, const float* __restrict__ b1,
                            const float* __restrict__ w2, float* __restrict__ tbl)
{
  __shared__ float red[256][4];
  int t = blockIdx.x;                  // 0..224
  int i = t / 15, j = t % 15;
  float c0 = 8.f * (float)(i - 7) / 7.f;
  float c1 = 8.f * (float)(j - 7) / 7.f;
  c0 = copysignf(log2f(fabsf(c0) + 1.f) / 3.f, c0);
  c1 = copysignf(log2f(fabsf(c1) + 1.f) / 3.f, c1);
  float a0 = 0.f, a1 = 0.f, a2 = 0.f, a3 = 0.f;
  for (int k = threadIdx.x; k < 512; k += 256) {
    float hd = fmaxf(c0 * w1[2*k] + c1 * w1[2*k+1] + b1[k], 0.f);
    a0 += hd * w2[k]; a1 += hd * w2[512+k]; a2 += hd * w2[1024+k]; a3 += hd * w2[1536+k];
  }
  red[threadIdx.x][0]=a0; red[threadIdx.x][1]=a1; red[threadIdx.x][2]=a2; red[threadIdx.x][3]=a3;
  __syncthreads();
  for (int s = 128; s > 0; s >>= 1) {
    if (threadIdx.x < (unsigned)s) {
      red[threadIdx.x][0] += red[threadIdx.x+s][0];
      red[threadIdx.x][1] += red[threadIdx.x+s][1];
      red[threadIdx.x][2] += red[threadIdx.x+s][2];
      red[threadIdx.x][3] += red[threadIdx.x+s][3];
    }
    __syncthreads();
  }
  if (threadIdx.x < 4) tbl[t*4 + threadIdx.x] = red[0][threadIdx.x];
}

// ---- prep: bias[h][n][m] = 16*sigmoid(tbl[rel(n,m)][h]) ----
__global__ void k_cpb_bias(const float* __restrict__ tbl, float* __restrict__ biasT)
{
  int idx = blockIdx.x * 256 + threadIdx.x;   // 0..16383
  int hh = idx >> 12, n = (idx >> 6) & 63, m = idx & 63;
  int rel = ((n >> 3) - (m >> 3) + 7) * 15 + ((n & 7) - (m & 7) + 7);
  float bv = tbl[rel * 4 + hh];
  biasT[idx] = 16.f / (1.f + expf(-bv));
}

// ---- main fused kernel: 1 block per window, wave h = head h ----
// LDS 32 KB: s_x (16 KB, x then O) + 4 KB/head private scratch (vT,q,k,P0,P1).
// __launch_bounds__(256,4): cap 128 VGPR -> 4 blocks/CU (16 waves).
__global__ __launch_bounds__(256, 4) void k_wmsa(
    const float* __restrict__ x, const float* __restrict__ mask,
    const unsigned short* __restrict__ wqkv, const unsigned short* __restrict__ wproj,
    const float* __restrict__ q_bias, const float* __restrict__ v_bias,
    const float* __restrict__ biasT, const float* __restrict__ scale4,
    const float* __restrict__ proj_b, float* __restrict__ out)
{
  __shared__ char s_x[64 * 256];     // 16KB: x bf16 swizzled; later O [n][c] bf16
  __shared__ char s_scr[4][4096];    // 4KB per head: vT -> q -> k -> P0 -> P1

  const int b    = blockIdx.x;
  const int tid  = threadIdx.x;
  const int lane = tid & 63;
  const int h    = tid >> 6;
  const int l15  = lane & 15;
  const int lh   = lane >> 4;
  const int swq  = ((l15 ^ (l15 >> 2)) & 3) << 4;  // 64B-row swizzle (rows keyed by l15)
  const int swv  = (l15 & 7) << 4;                 // 128B-row swizzle
  const floatx4 zf4 = {0.f, 0.f, 0.f, 0.f};
  char* scr = s_scr[h];

  // ---- Phase 0: stage x tile (64x128 fp32) -> bf16 swizzled LDS ----
  {
    const float* xb = x + (size_t)b * 8192;
    int r = tid >> 2;
    #pragma unroll
    for (int cc = 0; cc < 8; ++cc) {
      int c = (tid & 3) + cc * 4;
      float4 v = reinterpret_cast<const float4*>(xb)[r * 32 + c];
      uint2 w; w.x = pkbf(v.x, v.y); w.y = pkbf(v.z, v.w);
      *reinterpret_cast<uint2*>(s_x + r * 256 + ((c * 8) ^ ((r & 7) << 4))) = w;
    }
  }
  __syncthreads();

  // ---- Phase 1a: v = x @ Wv^T (C: row=token m, col=feat d) ----
  floatx4 vacc[4][2];
  #pragma unroll
  for (int mt = 0; mt < 4; ++mt) { vacc[mt][0] = zf4; vacc[mt][1] = zf4; }
  #pragma unroll
  for (int kk = 0; kk < 4; ++kk) {
    bf16x8 xf[4];
    #pragma unroll
    for (int tt = 0; tt < 4; ++tt) {
      int row = tt * 16 + l15;
      xf[tt] = *reinterpret_cast<const bf16x8*>(
          s_x + row * 256 + (((kk * 32 + lh * 8) * 2) ^ ((row & 7) << 4)));
    }
    #pragma unroll
    for (int ft = 0; ft < 2; ++ft) {
      bf16x8 wv = *reinterpret_cast<const bf16x8*>(
          wqkv + (size_t)(256 + h * 32 + ft * 16 + l15) * 128 + kk * 32 + lh * 8);
      #pragma unroll
      for (int mt = 0; mt < 4; ++mt)
        vacc[mt][ft] = __builtin_amdgcn_mfma_f32_16x16x32_bf16(xf[mt], wv, vacc[mt][ft], 0, 0, 0);
    }
  }
  // v bias; vT[d][m] (32 rows x 128B) into scr; then consume into vf frags
  {
    const float vb0 = v_bias[h * 32 + l15], vb1 = v_bias[h * 32 + 16 + l15];
    #pragma unroll
    for (int mt = 0; mt < 4; ++mt) {
      #pragma unroll
      for (int ft = 0; ft < 2; ++ft) {
        float vb = ft ? vb1 : vb0;
        uint2 w;
        w.x = pkbf(vacc[mt][ft][0] + vb, vacc[mt][ft][1] + vb);
        w.y = pkbf(vacc[mt][ft][2] + vb, vacc[mt][ft][3] + vb);
        *reinterpret_cast<uint2*>(scr + (ft * 16 + l15) * 128 + ((mt * 32 + lh * 8) ^ swv)) = w;
      }
    }
  }
  bf16x8 vf[2][2];   // [dt][kk-half]: A-frag rows d=dt*16+l15, k=m=kk*32+lh*8+j
  #pragma unroll
  for (int dt = 0; dt < 2; ++dt)
    #pragma unroll
    for (int k2 = 0; k2 < 2; ++k2)
      vf[dt][k2] = *reinterpret_cast<const bf16x8*>(
          scr + (dt * 16 + l15) * 128 + ((k2 * 64 + lh * 16) ^ swv));

  // ---- Phase 1b: q^T,k^T = W_qk @ x^T (C: row=feat, col=token) ----
  floatx4 qk[4][4];   // [ff: q0,q1,k0,k1][token tile]
  #pragma unroll
  for (int ff = 0; ff < 4; ++ff)
    #pragma unroll
    for (int tt = 0; tt < 4; ++tt) qk[ff][tt] = zf4;
  #pragma unroll
  for (int kk = 0; kk < 4; ++kk) {
    bf16x8 xf[4];
    #pragma unroll
    for (int tt = 0; tt < 4; ++tt) {
      int row = tt * 16 + l15;
      xf[tt] = *reinterpret_cast<const bf16x8*>(
          s_x + row * 256 + (((kk * 32 + lh * 8) * 2) ^ ((row & 7) << 4)));
    }
    #pragma unroll
    for (int ff = 0; ff < 4; ++ff) {
      int fb = (ff < 2) ? (h * 32 + ff * 16) : (128 + h * 32 + (ff - 2) * 16);
      bf16x8 wf = *reinterpret_cast<const bf16x8*>(
          wqkv + (size_t)(fb + l15) * 128 + kk * 32 + lh * 8);
      #pragma unroll
      for (int tt = 0; tt < 4; ++tt)
        qk[ff][tt] = __builtin_amdgcn_mfma_f32_16x16x32_bf16(wf, xf[tt], qk[ff][tt], 0, 0, 0);
    }
  }
  // q bias + lane-local cosine norms (token n = tt*16+l15; feat in regs/lh)
  {
    floatx4 qb0 = *reinterpret_cast<const floatx4*>(q_bias + h * 32 + lh * 4);
    floatx4 qb1 = *reinterpret_cast<const floatx4*>(q_bias + h * 32 + 16 + lh * 4);
    #pragma unroll
    for (int tt = 0; tt < 4; ++tt)
      #pragma unroll
      for (int r = 0; r < 4; ++r) { qk[0][tt][r] += qb0[r]; qk[1][tt][r] += qb1[r]; }
  }
  {
    const float sc = scale4[h];
    #pragma unroll
    for (int tt = 0; tt < 4; ++tt) {
      float sq = 0.f, sk = 0.f;
      #pragma unroll
      for (int r = 0; r < 4; ++r) {
        sq += qk[0][tt][r] * qk[0][tt][r] + qk[1][tt][r] * qk[1][tt][r];
        sk += qk[2][tt][r] * qk[2][tt][r] + qk[3][tt][r] * qk[3][tt][r];
      }
      sq += __shfl_xor(sq, 16); sq += __shfl_xor(sq, 32);
      sk += __shfl_xor(sk, 16); sk += __shfl_xor(sk, 32);
      float rq = sc  / fmaxf(sqrtf(sq), 1e-12f);
      float rk = 1.f / fmaxf(sqrtf(sk), 1e-12f);
      #pragma unroll
      for (int r = 0; r < 4; ++r) {
        qk[0][tt][r] *= rq; qk[1][tt][r] *= rq;
        qk[2][tt][r] *= rk; qk[3][tt][r] *= rk;
      }
    }
  }

  // ---- q transpose through scr (4KB: [64 tok][64B]) ----
  bf16x8 qf[4], kf[4];
  #pragma unroll
  for (int tt = 0; tt < 4; ++tt) {
    int rowb = (16 * tt + l15) * 64;
    #pragma unroll
    for (int ff = 0; ff < 2; ++ff) {
      uint2 w;
      w.x = pkbf(qk[ff][tt][0], qk[ff][tt][1]);
      w.y = pkbf(qk[ff][tt][2], qk[ff][tt][3]);
      *reinterpret_cast<uint2*>(scr + rowb + ((ff * 32 + lh * 8) ^ swq)) = w;
    }
  }
  #pragma unroll
  for (int tt = 0; tt < 4; ++tt)
    qf[tt] = *reinterpret_cast<const bf16x8*>(scr + (16 * tt + l15) * 64 + ((lh * 16) ^ swq));
  // ---- k transpose through scr ----
  #pragma unroll
  for (int tt = 0; tt < 4; ++tt) {
    int rowb = (16 * tt + l15) * 64;
    #pragma unroll
    for (int ff = 0; ff < 2; ++ff) {
      uint2 w;
      w.x = pkbf(qk[2 + ff][tt][0], qk[2 + ff][tt][1]);
      w.y = pkbf(qk[2 + ff][tt][2], qk[2 + ff][tt][3]);
      *reinterpret_cast<uint2*>(scr + rowb + ((ff * 32 + lh * 8) ^ swq)) = w;
    }
  }
  #pragma unroll
  for (int tt = 0; tt < 4; ++tt)
    kf[tt] = *reinterpret_cast<const bf16x8*>(scr + (16 * tt + l15) * 64 + ((lh * 16) ^ swq));

  // ---- Phase 2: S^T = kn @ qn^T (lane: row m=tm*16+lh*4+r, col n=tn*16+l15) ----
  floatx4 sacc[4][4];
  #pragma unroll
  for (int tm = 0; tm < 4; ++tm)
    #pragma unroll
    for (int tn = 0; tn < 4; ++tn)
      sacc[tm][tn] = __builtin_amdgcn_mfma_f32_16x16x32_bf16(kf[tm], qf[tn], zf4, 0, 0, 0);

  // ---- Phase 3: +bias +mask, exp (bounded logits), col sums ----
  floatx4 rs;
  {
    const float* bh = biasT + h * 4096;
    const float* mw = mask + (size_t)(b & 255) * 4096;
    #pragma unroll
    for (int tn = 0; tn < 4; ++tn) {
      floatx4 bb[4], mm[4];
      #pragma unroll
      for (int tm = 0; tm < 4; ++tm) {
        int off = (tn * 16 + l15) * 64 + tm * 16 + lh * 4;
        bb[tm] = *reinterpret_cast<const floatx4*>(bh + off);
        mm[tm] = *reinterpret_cast<const floatx4*>(mw + off);
      }
      float sum = 0.f;
      #pragma unroll
      for (int tm = 0; tm < 4; ++tm) {
        float e0 = __expf(sacc[tm][tn][0] + bb[tm][0] + mm[tm][0]);
        float e1 = __expf(sacc[tm][tn][1] + bb[tm][1] + mm[tm][1]);
        float e2 = __expf(sacc[tm][tn][2] + bb[tm][2] + mm[tm][2]);
        float e3 = __expf(sacc[tm][tn][3] + bb[tm][3] + mm[tm][3]);
        sacc[tm][tn][0] = e0; sacc[tm][tn][1] = e1;
        sacc[tm][tn][2] = e2; sacc[tm][tn][3] = e3;
        sum += (e0 + e1) + (e2 + e3);
      }
      sum += __shfl_xor(sum, 16); sum += __shfl_xor(sum, 32);
      rs[tn] = 1.f / sum;
    }
  }

  // ---- Phase 4: O^T = V^T @ P^T, P in two 4KB half-transposes through scr ----
  floatx4 oacc[2][4];
  #pragma unroll
  for (int dt = 0; dt < 2; ++dt)
    #pragma unroll
    for (int nt = 0; nt < 4; ++nt) oacc[dt][nt] = zf4;
  #pragma unroll
  for (int k2 = 0; k2 < 2; ++k2) {
    // write P half: rows n (64 x 64B), cols m' = m - k2*32
    #pragma unroll
    for (int tn = 0; tn < 4; ++tn) {
      int rowb = (16 * tn + l15) * 64;
      #pragma unroll
      for (int t2 = 0; t2 < 2; ++t2) {
        floatx4 pv = sacc[k2 * 2 + t2][tn];
        uint2 w;
        w.x = pkbf(pv[0], pv[1]); w.y = pkbf(pv[2], pv[3]);
        *reinterpret_cast<uint2*>(scr + rowb + ((t2 * 32 + lh * 8) ^ swq)) = w;
      }
    }
    #pragma unroll
    for (int nt = 0; nt < 4; ++nt) {
      bf16x8 pf = *reinterpret_cast<const bf16x8*>(
          scr + (nt * 16 + l15) * 64 + ((lh * 16) ^ swq));
      #pragma unroll
      for (int dt = 0; dt < 2; ++dt)
        oacc[dt][nt] = __builtin_amdgcn_mfma_f32_16x16x32_bf16(vf[dt][k2], pf, oacc[dt][nt], 0, 0, 0);
    }
  }
  __syncthreads();   // all waves done with s_x (phase 1) before O overwrites it

  // O (scaled by 1/rowsum) -> s_x as [n][c] bf16, b64-packed writes
  #pragma unroll
  for (int dt = 0; dt < 2; ++dt) {
    #pragma unroll
    for (int nt = 0; nt < 4; ++nt) {
      int n = nt * 16 + l15;
      uint2 w;
      w.x = pkbf(oacc[dt][nt][0] * rs[nt], oacc[dt][nt][1] * rs[nt]);
      w.y = pkbf(oacc[dt][nt][2] * rs[nt], oacc[dt][nt][3] * rs[nt]);
      *reinterpret_cast<uint2*>(
          s_x + n * 256 + (((h * 32 + dt * 16 + lh * 4) * 2) ^ ((n & 7) << 4))) = w;
    }
  }
  __syncthreads();

  // ---- Phase 5: proj GEMM + bias, fp32 store ----
  floatx4 pacc[4][2];
  #pragma unroll
  for (int mt = 0; mt < 4; ++mt) { pacc[mt][0] = zf4; pacc[mt][1] = zf4; }
  #pragma unroll
  for (int kk = 0; kk < 4; ++kk) {
    bf16x8 of[4];
    #pragma unroll
    for (int mt = 0; mt < 4; ++mt) {
      int row = mt * 16 + l15;
      of[mt] = *reinterpret_cast<const bf16x8*>(
          s_x + row * 256 + (((kk * 32 + lh * 8) * 2) ^ ((row & 7) << 4)));
    }
    #pragma unroll
    for (int ft = 0; ft < 2; ++ft) {
      bf16x8 wp = *reinterpret_cast<const bf16x8*>(
          wproj + (size_t)(h * 32 + ft * 16 + l15) * 128 + kk * 32 + lh * 8);
      #pragma unroll
      for (int mt = 0; mt < 4; ++mt)
        pacc[mt][ft] = __builtin_amdgcn_mfma_f32_16x16x32_bf16(of[mt], wp, pacc[mt][ft], 0, 0, 0);
    }
  }
  {
    float pb0 = proj_b[h * 32 + l15], pb1 = proj_b[h * 32 + 16 + l15];
    float* ob = out + (size_t)b * 8192;
    #pragma unroll
    for (int mt = 0; mt < 4; ++mt)
      #pragma unroll
      for (int r = 0; r < 4; ++r) {
        int n = mt * 16 + lh * 4 + r;
        ob[n * 128 + h * 32 + l15]      = pacc[mt][0][r] + pb0;
        ob[n * 128 + h * 32 + 16 + l15] = pacc[mt][1][r] + pb1;
      }
  }
}

extern "C" void kernel_launch(void* const* d_in, const int* in_sizes, int n_in,
                              void* d_out, int out_size, void* d_ws, size_t ws_size,
                              hipStream_t stream)
{
  const float* x    = (const float*)d_in[0];
  const float* mask = (const float*)d_in[1];
  const float* qkvw = (const float*)d_in[2];
  const float* qb   = (const float*)d_in[3];
  const float* vb   = (const float*)d_in[4];
  const float* ls   = (const float*)d_in[5];
  const float* w1   = (const float*)d_in[6];
  const float* b1   = (const float*)d_in[7];
  const float* w2   = (const float*)d_in[8];
  const float* pw   = (const float*)d_in[9];
  const float* pb   = (const float*)d_in[10];
  float* out = (float*)d_out;
  char* ws = (char*)d_ws;

  unsigned short* wsQ = (unsigned short*)ws;   // qkv bf16 [0,49152) + proj bf16 [49152,65536)
  float* wsBias  = (float*)(ws + WS_BIAS);
  float* wsScale = (float*)(ws + WS_SCALE);
  float* wsTbl   = (float*)(ws + WS_TBL);

  hipLaunchKernelGGL(k_prep_weights, dim3(64), dim3(256), 0, stream, qkvw, pw, ls, wsQ, wsScale);
  hipLaunchKernelGGL(k_cpb_table, dim3(225), dim3(256), 0, stream, w1, b1, w2, wsTbl);
  hipLaunchKernelGGL(k_cpb_bias, dim3(64), dim3(256), 0, stream, wsTbl, wsBias);
  hipLaunchKernelGGL(k_wmsa, dim3(8192), dim3(256), 0, stream, x, mask,
                     wsQ, wsQ + 49152, qb, vb, wsBias, wsScale, pb, out);
}

// Round 5
// 355.798 us; speedup vs baseline: 1.0079x; 1.0079x over previous
//
#include <hip/hip_runtime.h>

typedef __attribute__((ext_vector_type(8))) __bf16 bf16x8;
typedef __attribute__((ext_vector_type(4))) float floatx4;

#define WS_BIAS  131072   // 16384 f32 : 16*sigmoid(cpb) per [h][n][m]
#define WS_SCALE 196608   // 4 f32     : exp(min(logit_scale, log 100))
#define WS_TBL   196640   // 900 f32   : cpb table (225 x 4)

static __device__ __forceinline__ unsigned short f2bf_u(float f) {
  union { __bf16 b; unsigned short u; } cv; cv.b = (__bf16)f; return cv.u;
}
static __device__ __forceinline__ unsigned pkbf(float lo, float hi) {
  union { __bf16 b[2]; unsigned u; } cv; cv.b[0] = (__bf16)lo; cv.b[1] = (__bf16)hi; return cv.u;
}

// ---- prep: fp32 weights -> bf16 in ws; logit scale ----
__global__ void k_prep_weights(const float* __restrict__ qkv_w,
                               const float* __restrict__ proj_w,
                               const float* __restrict__ logit_scale,
                               unsigned short* __restrict__ wsQ,
                               float* __restrict__ wsScale)
{
  int t = blockIdx.x * 256 + threadIdx.x;   // 0..16383
  int i4 = t * 4;
  float4 v;
  if (i4 < 49152) v = *reinterpret_cast<const float4*>(qkv_w + i4);
  else            v = *reinterpret_cast<const float4*>(proj_w + (i4 - 49152));
  ushort4 pk;
  pk.x = f2bf_u(v.x); pk.y = f2bf_u(v.y); pk.z = f2bf_u(v.z); pk.w = f2bf_u(v.w);
  *reinterpret_cast<ushort4*>(wsQ + i4) = pk;
  if (t < 4) wsScale[t] = expf(fminf(logit_scale[t], 4.6051702f));
}

// ---- prep: CPB MLP table (225 x 4), one block per table row ----
__global__ void k_cpb_table(const float* __restrict__ w1, const float* __restrict__ b1,
                            const float* __restrict__ w2, float* __restrict__ tbl)
{
  __shared__ float red[256][4];
  int t = blockIdx.x;                  // 0..224
  int i = t / 15, j = t % 15;
  float c0 = 8.f * (float)(i - 7) / 7.f;
  float c1 = 8.f * (float)(j - 7) / 7.f;
  c0 = copysignf(log2f(fabsf(c0) + 1.f) / 3.f, c0);
  c1 = copysignf(log2f(fabsf(c1) + 1.f) / 3.f, c1);
  float a0 = 0.f, a1 = 0.f, a2 = 0.f, a3 = 0.f;
  for (int k = threadIdx.x; k < 512; k += 256) {
    float hd = fmaxf(c0 * w1[2*k] + c1 * w1[2*k+1] + b1[k], 0.f);
    a0 += hd * w2[k]; a1 += hd * w2[512+k]; a2 += hd * w2[1024+k]; a3 += hd * w2[1536+k];
  }
  red[threadIdx.x][0]=a0; red[threadIdx.x][1]=a1; red[threadIdx.x][2]=a2; red[threadIdx.x][3]=a3;
  __syncthreads();
  for (int s = 128; s > 0; s >>= 1) {
    if (threadIdx.x < (unsigned)s) {
      red[threadIdx.x][0] += red[threadIdx.x+s][0];
      red[threadIdx.x][1] += red[threadIdx.x+s][1];
      red[threadIdx.x][2] += red[threadIdx.x+s][2];
      red[threadIdx.x][3] += red[threadIdx.x+s][3];
    }
    __syncthreads();
  }
  if (threadIdx.x < 4) tbl[t*4 + threadIdx.x] = red[0][threadIdx.x];
}

// ---- prep: bias[h][n][m] = 16*sigmoid(tbl[rel(n,m)][h]) ----
__global__ void k_cpb_bias(const float* __restrict__ tbl, float* __restrict__ biasT)
{
  int idx = blockIdx.x * 256 + threadIdx.x;   // 0..16383
  int hh = idx >> 12, n = (idx >> 6) & 63, m = idx & 63;
  int rel = ((n >> 3) - (m >> 3) + 7) * 15 + ((n & 7) - (m & 7) + 7);
  float bv = tbl[rel * 4 + hh];
  biasT[idx] = 16.f / (1.f + expf(-bv));
}

// ---- main fused kernel: 1 block per window, wave h = head h ----
// LDS 32 KB: s_x (16 KB, x then O) + 4 KB/head private scratch (vT,q,k,P0,P1).
// amdgpu_waves_per_eu(4,4): pin allocator at the 128-VGPR tier (4 waves/EU);
// min-only launch_bounds let the compiler squeeze to 64 VGPR + spills (R2/R4).
__global__ __launch_bounds__(256)
__attribute__((amdgpu_waves_per_eu(4, 4))) void k_wmsa(
    const float* __restrict__ x, const float* __restrict__ mask,
    const unsigned short* __restrict__ wqkv, const unsigned short* __restrict__ wproj,
    const float* __restrict__ q_bias, const float* __restrict__ v_bias,
    const float* __restrict__ biasT, const float* __restrict__ scale4,
    const float* __restrict__ proj_b, float* __restrict__ out)
{
  __shared__ char s_x[64 * 256];     // 16KB: x bf16 swizzled; later O [n][c] bf16
  __shared__ char s_scr[4][4096];    // 4KB per head: vT -> q -> k -> P0 -> P1

  const int b    = blockIdx.x;
  const int tid  = threadIdx.x;
  const int lane = tid & 63;
  const int h    = tid >> 6;
  const int l15  = lane & 15;
  const int lh   = lane >> 4;
  const int swq  = ((l15 ^ (l15 >> 2)) & 3) << 4;  // 64B-row swizzle (rows keyed by l15)
  const int swv  = (l15 & 7) << 4;                 // 128B-row swizzle
  const floatx4 zf4 = {0.f, 0.f, 0.f, 0.f};
  char* scr = s_scr[h];

  // ---- Phase 0: stage x tile (64x128 fp32) -> bf16 swizzled LDS ----
  {
    const float* xb = x + (size_t)b * 8192;
    int r = tid >> 2;
    #pragma unroll
    for (int cc = 0; cc < 8; ++cc) {
      int c = (tid & 3) + cc * 4;
      float4 v = reinterpret_cast<const float4*>(xb)[r * 32 + c];
      uint2 w; w.x = pkbf(v.x, v.y); w.y = pkbf(v.z, v.w);
      *reinterpret_cast<uint2*>(s_x + r * 256 + ((c * 8) ^ ((r & 7) << 4))) = w;
    }
  }
  __syncthreads();

  // ---- Phase 1a: v = x @ Wv^T (C: row=token m, col=feat d) ----
  floatx4 vacc[4][2];
  #pragma unroll
  for (int mt = 0; mt < 4; ++mt) { vacc[mt][0] = zf4; vacc[mt][1] = zf4; }
  #pragma unroll
  for (int kk = 0; kk < 4; ++kk) {
    bf16x8 xf[4];
    #pragma unroll
    for (int tt = 0; tt < 4; ++tt) {
      int row = tt * 16 + l15;
      xf[tt] = *reinterpret_cast<const bf16x8*>(
          s_x + row * 256 + (((kk * 32 + lh * 8) * 2) ^ ((row & 7) << 4)));
    }
    #pragma unroll
    for (int ft = 0; ft < 2; ++ft) {
      bf16x8 wv = *reinterpret_cast<const bf16x8*>(
          wqkv + (size_t)(256 + h * 32 + ft * 16 + l15) * 128 + kk * 32 + lh * 8);
      #pragma unroll
      for (int mt = 0; mt < 4; ++mt)
        vacc[mt][ft] = __builtin_amdgcn_mfma_f32_16x16x32_bf16(xf[mt], wv, vacc[mt][ft], 0, 0, 0);
    }
  }
  // v bias; vT[d][m] (32 rows x 128B) into scr; then consume into vf frags
  {
    const float vb0 = v_bias[h * 32 + l15], vb1 = v_bias[h * 32 + 16 + l15];
    #pragma unroll
    for (int mt = 0; mt < 4; ++mt) {
      #pragma unroll
      for (int ft = 0; ft < 2; ++ft) {
        float vb = ft ? vb1 : vb0;
        uint2 w;
        w.x = pkbf(vacc[mt][ft][0] + vb, vacc[mt][ft][1] + vb);
        w.y = pkbf(vacc[mt][ft][2] + vb, vacc[mt][ft][3] + vb);
        *reinterpret_cast<uint2*>(scr + (ft * 16 + l15) * 128 + ((mt * 32 + lh * 8) ^ swv)) = w;
      }
    }
  }
  bf16x8 vf[2][2];   // [dt][kk-half]: A-frag rows d=dt*16+l15, k=m=kk*32+lh*8+j
  #pragma unroll
  for (int dt = 0; dt < 2; ++dt)
    #pragma unroll
    for (int k2 = 0; k2 < 2; ++k2)
      vf[dt][k2] = *reinterpret_cast<const bf16x8*>(
          scr + (dt * 16 + l15) * 128 + ((k2 * 64 + lh * 16) ^ swv));

  // ---- Phase 1b: q^T,k^T = W_qk @ x^T (C: row=feat, col=token) ----
  floatx4 qk[4][4];   // [ff: q0,q1,k0,k1][token tile]
  #pragma unroll
  for (int ff = 0; ff < 4; ++ff)
    #pragma unroll
    for (int tt = 0; tt < 4; ++tt) qk[ff][tt] = zf4;
  #pragma unroll
  for (int kk = 0; kk < 4; ++kk) {
    bf16x8 xf[4];
    #pragma unroll
    for (int tt = 0; tt < 4; ++tt) {
      int row = tt * 16 + l15;
      xf[tt] = *reinterpret_cast<const bf16x8*>(
          s_x + row * 256 + (((kk * 32 + lh * 8) * 2) ^ ((row & 7) << 4)));
    }
    #pragma unroll
    for (int ff = 0; ff < 4; ++ff) {
      int fb = (ff < 2) ? (h * 32 + ff * 16) : (128 + h * 32 + (ff - 2) * 16);
      bf16x8 wf = *reinterpret_cast<const bf16x8*>(
          wqkv + (size_t)(fb + l15) * 128 + kk * 32 + lh * 8);
      #pragma unroll
      for (int tt = 0; tt < 4; ++tt)
        qk[ff][tt] = __builtin_amdgcn_mfma_f32_16x16x32_bf16(wf, xf[tt], qk[ff][tt], 0, 0, 0);
    }
  }
  // q bias + lane-local cosine norms (token n = tt*16+l15; feat in regs/lh)
  {
    floatx4 qb0 = *reinterpret_cast<const floatx4*>(q_bias + h * 32 + lh * 4);
    floatx4 qb1 = *reinterpret_cast<const floatx4*>(q_bias + h * 32 + 16 + lh * 4);
    #pragma unroll
    for (int tt = 0; tt < 4; ++tt)
      #pragma unroll
      for (int r = 0; r < 4; ++r) { qk[0][tt][r] += qb0[r]; qk[1][tt][r] += qb1[r]; }
  }
  {
    const float sc = scale4[h];
    #pragma unroll
    for (int tt = 0; tt < 4; ++tt) {
      float sq = 0.f, sk = 0.f;
      #pragma unroll
      for (int r = 0; r < 4; ++r) {
        sq += qk[0][tt][r] * qk[0][tt][r] + qk[1][tt][r] * qk[1][tt][r];
        sk += qk[2][tt][r] * qk[2][tt][r] + qk[3][tt][r] * qk[3][tt][r];
      }
      sq += __shfl_xor(sq, 16); sq += __shfl_xor(sq, 32);
      sk += __shfl_xor(sk, 16); sk += __shfl_xor(sk, 32);
      float rq = sc  / fmaxf(sqrtf(sq), 1e-12f);
      float rk = 1.f / fmaxf(sqrtf(sk), 1e-12f);
      #pragma unroll
      for (int r = 0; r < 4; ++r) {
        qk[0][tt][r] *= rq; qk[1][tt][r] *= rq;
        qk[2][tt][r] *= rk; qk[3][tt][r] *= rk;
      }
    }
  }

  // ---- q transpose through scr (4KB: [64 tok][64B]) ----
  bf16x8 qf[4], kf[4];
  #pragma unroll
  for (int tt = 0; tt < 4; ++tt) {
    int rowb = (16 * tt + l15) * 64;
    #pragma unroll
    for (int ff = 0; ff < 2; ++ff) {
      uint2 w;
      w.x = pkbf(qk[ff][tt][0], qk[ff][tt][1]);
      w.y = pkbf(qk[ff][tt][2], qk[ff][tt][3]);
      *reinterpret_cast<uint2*>(scr + rowb + ((ff * 32 + lh * 8) ^ swq)) = w;
    }
  }
  #pragma unroll
  for (int tt = 0; tt < 4; ++tt)
    qf[tt] = *reinterpret_cast<const bf16x8*>(scr + (16 * tt + l15) * 64 + ((lh * 16) ^ swq));
  // ---- k transpose through scr ----
  #pragma unroll
  for (int tt = 0; tt < 4; ++tt) {
    int rowb = (16 * tt + l15) * 64;
    #pragma unroll
    for (int ff = 0; ff < 2; ++ff) {
      uint2 w;
      w.x = pkbf(qk[2 + ff][tt][0], qk[2 + ff][tt][1]);
      w.y = pkbf(qk[2 + ff][tt][2], qk[2 + ff][tt][3]);
      *reinterpret_cast<uint2*>(scr + rowb + ((ff * 32 + lh * 8) ^ swq)) = w;
    }
  }
  #pragma unroll
  for (int tt = 0; tt < 4; ++tt)
    kf[tt] = *reinterpret_cast<const bf16x8*>(scr + (16 * tt + l15) * 64 + ((lh * 16) ^ swq));

  // ---- Phase 2: S^T = kn @ qn^T (lane: row m=tm*16+lh*4+r, col n=tn*16+l15) ----
  floatx4 sacc[4][4];
  #pragma unroll
  for (int tm = 0; tm < 4; ++tm)
    #pragma unroll
    for (int tn = 0; tn < 4; ++tn)
      sacc[tm][tn] = __builtin_amdgcn_mfma_f32_16x16x32_bf16(kf[tm], qf[tn], zf4, 0, 0, 0);

  // ---- Phase 3: +bias +mask, exp (bounded logits), col sums ----
  floatx4 rs;
  {
    const float* bh = biasT + h * 4096;
    const float* mw = mask + (size_t)(b & 255) * 4096;
    #pragma unroll
    for (int tn = 0; tn < 4; ++tn) {
      floatx4 bb[4], mm[4];
      #pragma unroll
      for (int tm = 0; tm < 4; ++tm) {
        int off = (tn * 16 + l15) * 64 + tm * 16 + lh * 4;
        bb[tm] = *reinterpret_cast<const floatx4*>(bh + off);
        mm[tm] = *reinterpret_cast<const floatx4*>(mw + off);
      }
      float sum = 0.f;
      #pragma unroll
      for (int tm = 0; tm < 4; ++tm) {
        float e0 = __expf(sacc[tm][tn][0] + bb[tm][0] + mm[tm][0]);
        float e1 = __expf(sacc[tm][tn][1] + bb[tm][1] + mm[tm][1]);
        float e2 = __expf(sacc[tm][tn][2] + bb[tm][2] + mm[tm][2]);
        float e3 = __expf(sacc[tm][tn][3] + bb[tm][3] + mm[tm][3]);
        sacc[tm][tn][0] = e0; sacc[tm][tn][1] = e1;
        sacc[tm][tn][2] = e2; sacc[tm][tn][3] = e3;
        sum += (e0 + e1) + (e2 + e3);
      }
      sum += __shfl_xor(sum, 16); sum += __shfl_xor(sum, 32);
      rs[tn] = 1.f / sum;
    }
  }

  // ---- Phase 4: O^T = V^T @ P^T, P in two 4KB half-transposes through scr ----
  floatx4 oacc[2][4];
  #pragma unroll
  for (int dt = 0; dt < 2; ++dt)
    #pragma unroll
    for (int nt = 0; nt < 4; ++nt) oacc[dt][nt] = zf4;
  #pragma unroll
  for (int k2 = 0; k2 < 2; ++k2) {
    // write P half: rows n (64 x 64B), cols m' = m - k2*32
    #pragma unroll
    for (int tn = 0; tn < 4; ++tn) {
      int rowb = (16 * tn + l15) * 64;
      #pragma unroll
      for (int t2 = 0; t2 < 2; ++t2) {
        floatx4 pv = sacc[k2 * 2 + t2][tn];
        uint2 w;
        w.x = pkbf(pv[0], pv[1]); w.y = pkbf(pv[2], pv[3]);
        *reinterpret_cast<uint2*>(scr + rowb + ((t2 * 32 + lh * 8) ^ swq)) = w;
      }
    }
    #pragma unroll
    for (int nt = 0; nt < 4; ++nt) {
      bf16x8 pf = *reinterpret_cast<const bf16x8*>(
          scr + (nt * 16 + l15) * 64 + ((lh * 16) ^ swq));
      #pragma unroll
      for (int dt = 0; dt < 2; ++dt)
        oacc[dt][nt] = __builtin_amdgcn_mfma_f32_16x16x32_bf16(vf[dt][k2], pf, oacc[dt][nt], 0, 0, 0);
    }
  }
  __syncthreads();   // all waves done with s_x (phase 1) before O overwrites it

  // O (scaled by 1/rowsum) -> s_x as [n][c] bf16, b64-packed writes
  #pragma unroll
  for (int dt = 0; dt < 2; ++dt) {
    #pragma unroll
    for (int nt = 0; nt < 4; ++nt) {
      int n = nt * 16 + l15;
      uint2 w;
      w.x = pkbf(oacc[dt][nt][0] * rs[nt], oacc[dt][nt][1] * rs[nt]);
      w.y = pkbf(oacc[dt][nt][2] * rs[nt], oacc[dt][nt][3] * rs[nt]);
      *reinterpret_cast<uint2*>(
          s_x + n * 256 + (((h * 32 + dt * 16 + lh * 4) * 2) ^ ((n & 7) << 4))) = w;
    }
  }
  __syncthreads();

  // ---- Phase 5: proj GEMM + bias, fp32 store ----
  floatx4 pacc[4][2];
  #pragma unroll
  for (int mt = 0; mt < 4; ++mt) { pacc[mt][0] = zf4; pacc[mt][1] = zf4; }
  #pragma unroll
  for (int kk = 0; kk < 4; ++kk) {
    bf16x8 of[4];
    #pragma unroll
    for (int mt = 0; mt < 4; ++mt) {
      int row = mt * 16 + l15;
      of[mt] = *reinterpret_cast<const bf16x8*>(
          s_x + row * 256 + (((kk * 32 + lh * 8) * 2) ^ ((row & 7) << 4)));
    }
    #pragma unroll
    for (int ft = 0; ft < 2; ++ft) {
      bf16x8 wp = *reinterpret_cast<const bf16x8*>(
          wproj + (size_t)(h * 32 + ft * 16 + l15) * 128 + kk * 32 + lh * 8);
      #pragma unroll
      for (int mt = 0; mt < 4; ++mt)
        pacc[mt][ft] = __builtin_amdgcn_mfma_f32_16x16x32_bf16(of[mt], wp, pacc[mt][ft], 0, 0, 0);
    }
  }
  {
    float pb0 = proj_b[h * 32 + l15], pb1 = proj_b[h * 32 + 16 + l15];
    float* ob = out + (size_t)b * 8192;
    #pragma unroll
    for (int mt = 0; mt < 4; ++mt)
      #pragma unroll
      for (int r = 0; r < 4; ++r) {
        int n = mt * 16 + lh * 4 + r;
        ob[n * 128 + h * 32 + l15]      = pacc[mt][0][r] + pb0;
        ob[n * 128 + h * 32 + 16 + l15] = pacc[mt][1][r] + pb1;
      }
  }
}

extern "C" void kernel_launch(void* const* d_in, const int* in_sizes, int n_in,
                              void* d_out, int out_size, void* d_ws, size_t ws_size,
                              hipStream_t stream)
{
  const float* x    = (const float*)d_in[0];
  const float* mask = (const float*)d_in[1];
  const float* qkvw = (const float*)d_in[2];
  const float* qb   = (const float*)d_in[3];
  const float* vb   = (const float*)d_in[4];
  const float* ls   = (const float*)d_in[5];
  const float* w1   = (const float*)d_in[6];
  const float* b1   = (const float*)d_in[7];
  const float* w2   = (const float*)d_in[8];
  const float* pw   = (const float*)d_in[9];
  const float* pb   = (const float*)d_in[10];
  float* out = (float*)d_out;
  char* ws = (char*)d_ws;

  unsigned short* wsQ = (unsigned short*)ws;   // qkv bf16 [0,49152) + proj bf16 [49152,65536)
  float* wsBias  = (float*)(ws + WS_BIAS);
  float* wsScale = (float*)(ws + WS_SCALE);
  float* wsTbl   = (float*)(ws + WS_TBL);

  hipLaunchKernelGGL(k_prep_weights, dim3(64), dim3(256), 0, stream, qkvw, pw, ls, wsQ, wsScale);
  hipLaunchKernelGGL(k_cpb_table, dim3(225), dim3(256), 0, stream, w1, b1, w2, wsTbl);
  hipLaunchKernelGGL(k_cpb_bias, dim3(64), dim3(256), 0, stream, wsTbl, wsBias);
  hipLaunchKernelGGL(k_wmsa, dim3(8192), dim3(256), 0, stream, x, mask,
                     wsQ, wsQ + 49152, qb, vb, wsBias, wsScale, pb, out);
}

// Round 6
// 324.731 us; speedup vs baseline: 1.1043x; 1.0957x over previous
//
#include <hip/hip_runtime.h>

typedef __attribute__((ext_vector_type(8))) __bf16 bf16x8;
typedef __attribute__((ext_vector_type(4))) float floatx4;

#define WS_BIAS  131072   // 16384 f32 : 16*sigmoid(cpb) per [h][n][m]
#define WS_SCALE 196608   // 4 f32     : exp(min(logit_scale, log 100))
#define WS_TBL   196640   // 900 f32   : cpb table (225 x 4)

static __device__ __forceinline__ unsigned short f2bf_u(float f) {
  union { __bf16 b; unsigned short u; } cv; cv.b = (__bf16)f; return cv.u;
}
static __device__ __forceinline__ unsigned pkbf(float lo, float hi) {
  union { __bf16 b[2]; unsigned u; } cv; cv.b[0] = (__bf16)lo; cv.b[1] = (__bf16)hi; return cv.u;
}

// ---- prep: fp32 weights -> bf16 in ws; logit scale ----
__global__ void k_prep_weights(const float* __restrict__ qkv_w,
                               const float* __restrict__ proj_w,
                               const float* __restrict__ logit_scale,
                               unsigned short* __restrict__ wsQ,
                               float* __restrict__ wsScale)
{
  int t = blockIdx.x * 256 + threadIdx.x;   // 0..16383
  int i4 = t * 4;
  float4 v;
  if (i4 < 49152) v = *reinterpret_cast<const float4*>(qkv_w + i4);
  else            v = *reinterpret_cast<const float4*>(proj_w + (i4 - 49152));
  ushort4 pk;
  pk.x = f2bf_u(v.x); pk.y = f2bf_u(v.y); pk.z = f2bf_u(v.z); pk.w = f2bf_u(v.w);
  *reinterpret_cast<ushort4*>(wsQ + i4) = pk;
  if (t < 4) wsScale[t] = expf(fminf(logit_scale[t], 4.6051702f));
}

// ---- prep: CPB MLP table (225 x 4), one block per table row ----
__global__ void k_cpb_table(const float* __restrict__ w1, const float* __restrict__ b1,
                            const float* __restrict__ w2, float* __restrict__ tbl)
{
  __shared__ float red[256][4];
  int t = blockIdx.x;                  // 0..224
  int i = t / 15, j = t % 15;
  float c0 = 8.f * (float)(i - 7) / 7.f;
  float c1 = 8.f * (float)(j - 7) / 7.f;
  c0 = copysignf(log2f(fabsf(c0) + 1.f) / 3.f, c0);
  c1 = copysignf(log2f(fabsf(c1) + 1.f) / 3.f, c1);
  float a0 = 0.f, a1 = 0.f, a2 = 0.f, a3 = 0.f;
  for (int k = threadIdx.x; k < 512; k += 256) {
    float hd = fmaxf(c0 * w1[2*k] + c1 * w1[2*k+1] + b1[k], 0.f);
    a0 += hd * w2[k]; a1 += hd * w2[512+k]; a2 += hd * w2[1024+k]; a3 += hd * w2[1536+k];
  }
  red[threadIdx.x][0]=a0; red[threadIdx.x][1]=a1; red[threadIdx.x][2]=a2; red[threadIdx.x][3]=a3;
  __syncthreads();
  for (int s = 128; s > 0; s >>= 1) {
    if (threadIdx.x < (unsigned)s) {
      red[threadIdx.x][0] += red[threadIdx.x+s][0];
      red[threadIdx.x][1] += red[threadIdx.x+s][1];
      red[threadIdx.x][2] += red[threadIdx.x+s][2];
      red[threadIdx.x][3] += red[threadIdx.x+s][3];
    }
    __syncthreads();
  }
  if (threadIdx.x < 4) tbl[t*4 + threadIdx.x] = red[0][threadIdx.x];
}

// ---- prep: bias[h][n][m] = 16*sigmoid(tbl[rel(n,m)][h]) ----
__global__ void k_cpb_bias(const float* __restrict__ tbl, float* __restrict__ biasT)
{
  int idx = blockIdx.x * 256 + threadIdx.x;   // 0..16383
  int hh = idx >> 12, n = (idx >> 6) & 63, m = idx & 63;
  int rel = ((n >> 3) - (m >> 3) + 7) * 15 + ((n & 7) - (m & 7) + 7);
  float bv = tbl[rel * 4 + hh];
  biasT[idx] = 16.f / (1.f + expf(-bv));
}

// ---- main fused kernel: 1 block per window, wave h = head h ----
// LDS 32 KB: s_x (16 KB, x then O) + 4 KB/head private scratch (vT,q,k,P0,P1).
// __launch_bounds__(256,2): min-waves=2 relaxes the allocator (R3: 112 VGPR,
// no spill). min-waves>=4 (R2/R4) or waves_per_eu(4,4) (R5) both made the
// allocator squeeze to 64 VGPR with ~180MB of spill traffic. With ~112-128
// VGPR the HW occupancy tier is 4 waves/SIMD; 32KB LDS allows 5 blocks/CU ->
// effective 4 blocks/CU.
__global__ __launch_bounds__(256, 2) void k_wmsa(
    const float* __restrict__ x, const float* __restrict__ mask,
    const unsigned short* __restrict__ wqkv, const unsigned short* __restrict__ wproj,
    const float* __restrict__ q_bias, const float* __restrict__ v_bias,
    const float* __restrict__ biasT, const float* __restrict__ scale4,
    const float* __restrict__ proj_b, float* __restrict__ out)
{
  __shared__ char s_x[64 * 256];     // 16KB: x bf16 swizzled; later O [n][c] bf16
  __shared__ char s_scr[4][4096];    // 4KB per head: vT -> q -> k -> P0 -> P1

  const int b    = blockIdx.x;
  const int tid  = threadIdx.x;
  const int lane = tid & 63;
  const int h    = tid >> 6;
  const int l15  = lane & 15;
  const int lh   = lane >> 4;
  const int swq  = ((l15 ^ (l15 >> 2)) & 3) << 4;  // 64B-row swizzle (rows keyed by l15)
  const int swv  = (l15 & 7) << 4;                 // 128B-row swizzle
  const floatx4 zf4 = {0.f, 0.f, 0.f, 0.f};
  char* scr = s_scr[h];

  // ---- Phase 0: stage x tile (64x128 fp32) -> bf16 swizzled LDS ----
  {
    const float* xb = x + (size_t)b * 8192;
    int r = tid >> 2;
    #pragma unroll
    for (int cc = 0; cc < 8; ++cc) {
      int c = (tid & 3) + cc * 4;
      float4 v = reinterpret_cast<const float4*>(xb)[r * 32 + c];
      uint2 w; w.x = pkbf(v.x, v.y); w.y = pkbf(v.z, v.w);
      *reinterpret_cast<uint2*>(s_x + r * 256 + ((c * 8) ^ ((r & 7) << 4))) = w;
    }
  }
  __syncthreads();

  // ---- Phase 1a: v = x @ Wv^T (C: row=token m, col=feat d) ----
  floatx4 vacc[4][2];
  #pragma unroll
  for (int mt = 0; mt < 4; ++mt) { vacc[mt][0] = zf4; vacc[mt][1] = zf4; }
  #pragma unroll
  for (int kk = 0; kk < 4; ++kk) {
    bf16x8 xf[4];
    #pragma unroll
    for (int tt = 0; tt < 4; ++tt) {
      int row = tt * 16 + l15;
      xf[tt] = *reinterpret_cast<const bf16x8*>(
          s_x + row * 256 + (((kk * 32 + lh * 8) * 2) ^ ((row & 7) << 4)));
    }
    #pragma unroll
    for (int ft = 0; ft < 2; ++ft) {
      bf16x8 wv = *reinterpret_cast<const bf16x8*>(
          wqkv + (size_t)(256 + h * 32 + ft * 16 + l15) * 128 + kk * 32 + lh * 8);
      #pragma unroll
      for (int mt = 0; mt < 4; ++mt)
        vacc[mt][ft] = __builtin_amdgcn_mfma_f32_16x16x32_bf16(xf[mt], wv, vacc[mt][ft], 0, 0, 0);
    }
  }
  // v bias; vT[d][m] (32 rows x 128B) into scr; then consume into vf frags
  {
    const float vb0 = v_bias[h * 32 + l15], vb1 = v_bias[h * 32 + 16 + l15];
    #pragma unroll
    for (int mt = 0; mt < 4; ++mt) {
      #pragma unroll
      for (int ft = 0; ft < 2; ++ft) {
        float vb = ft ? vb1 : vb0;
        uint2 w;
        w.x = pkbf(vacc[mt][ft][0] + vb, vacc[mt][ft][1] + vb);
        w.y = pkbf(vacc[mt][ft][2] + vb, vacc[mt][ft][3] + vb);
        *reinterpret_cast<uint2*>(scr + (ft * 16 + l15) * 128 + ((mt * 32 + lh * 8) ^ swv)) = w;
      }
    }
  }
  bf16x8 vf[2][2];   // [dt][kk-half]: A-frag rows d=dt*16+l15, k=m=kk*32+lh*8+j
  #pragma unroll
  for (int dt = 0; dt < 2; ++dt)
    #pragma unroll
    for (int k2 = 0; k2 < 2; ++k2)
      vf[dt][k2] = *reinterpret_cast<const bf16x8*>(
          scr + (dt * 16 + l15) * 128 + ((k2 * 64 + lh * 16) ^ swv));

  // ---- Phase 1b: q^T,k^T = W_qk @ x^T (C: row=feat, col=token) ----
  floatx4 qk[4][4];   // [ff: q0,q1,k0,k1][token tile]
  #pragma unroll
  for (int ff = 0; ff < 4; ++ff)
    #pragma unroll
    for (int tt = 0; tt < 4; ++tt) qk[ff][tt] = zf4;
  #pragma unroll
  for (int kk = 0; kk < 4; ++kk) {
    bf16x8 xf[4];
    #pragma unroll
    for (int tt = 0; tt < 4; ++tt) {
      int row = tt * 16 + l15;
      xf[tt] = *reinterpret_cast<const bf16x8*>(
          s_x + row * 256 + (((kk * 32 + lh * 8) * 2) ^ ((row & 7) << 4)));
    }
    #pragma unroll
    for (int ff = 0; ff < 4; ++ff) {
      int fb = (ff < 2) ? (h * 32 + ff * 16) : (128 + h * 32 + (ff - 2) * 16);
      bf16x8 wf = *reinterpret_cast<const bf16x8*>(
          wqkv + (size_t)(fb + l15) * 128 + kk * 32 + lh * 8);
      #pragma unroll
      for (int tt = 0; tt < 4; ++tt)
        qk[ff][tt] = __builtin_amdgcn_mfma_f32_16x16x32_bf16(wf, xf[tt], qk[ff][tt], 0, 0, 0);
    }
  }
  // q bias + lane-local cosine norms (token n = tt*16+l15; feat in regs/lh)
  {
    floatx4 qb0 = *reinterpret_cast<const floatx4*>(q_bias + h * 32 + lh * 4);
    floatx4 qb1 = *reinterpret_cast<const floatx4*>(q_bias + h * 32 + 16 + lh * 4);
    #pragma unroll
    for (int tt = 0; tt < 4; ++tt)
      #pragma unroll
      for (int r = 0; r < 4; ++r) { qk[0][tt][r] += qb0[r]; qk[1][tt][r] += qb1[r]; }
  }
  {
    const float sc = scale4[h];
    #pragma unroll
    for (int tt = 0; tt < 4; ++tt) {
      float sq = 0.f, sk = 0.f;
      #pragma unroll
      for (int r = 0; r < 4; ++r) {
        sq += qk[0][tt][r] * qk[0][tt][r] + qk[1][tt][r] * qk[1][tt][r];
        sk += qk[2][tt][r] * qk[2][tt][r] + qk[3][tt][r] * qk[3][tt][r];
      }
      sq += __shfl_xor(sq, 16); sq += __shfl_xor(sq, 32);
      sk += __shfl_xor(sk, 16); sk += __shfl_xor(sk, 32);
      float rq = sc  / fmaxf(sqrtf(sq), 1e-12f);
      float rk = 1.f / fmaxf(sqrtf(sk), 1e-12f);
      #pragma unroll
      for (int r = 0; r < 4; ++r) {
        qk[0][tt][r] *= rq; qk[1][tt][r] *= rq;
        qk[2][tt][r] *= rk; qk[3][tt][r] *= rk;
      }
    }
  }

  // ---- q transpose through scr (4KB: [64 tok][64B]) ----
  bf16x8 qf[4], kf[4];
  #pragma unroll
  for (int tt = 0; tt < 4; ++tt) {
    int rowb = (16 * tt + l15) * 64;
    #pragma unroll
    for (int ff = 0; ff < 2; ++ff) {
      uint2 w;
      w.x = pkbf(qk[ff][tt][0], qk[ff][tt][1]);
      w.y = pkbf(qk[ff][tt][2], qk[ff][tt][3]);
      *reinterpret_cast<uint2*>(scr + rowb + ((ff * 32 + lh * 8) ^ swq)) = w;
    }
  }
  #pragma unroll
  for (int tt = 0; tt < 4; ++tt)
    qf[tt] = *reinterpret_cast<const bf16x8*>(scr + (16 * tt + l15) * 64 + ((lh * 16) ^ swq));
  // ---- k transpose through scr ----
  #pragma unroll
  for (int tt = 0; tt < 4; ++tt) {
    int rowb = (16 * tt + l15) * 64;
    #pragma unroll
    for (int ff = 0; ff < 2; ++ff) {
      uint2 w;
      w.x = pkbf(qk[2 + ff][tt][0], qk[2 + ff][tt][1]);
      w.y = pkbf(qk[2 + ff][tt][2], qk[2 + ff][tt][3]);
      *reinterpret_cast<uint2*>(scr + rowb + ((ff * 32 + lh * 8) ^ swq)) = w;
    }
  }
  #pragma unroll
  for (int tt = 0; tt < 4; ++tt)
    kf[tt] = *reinterpret_cast<const bf16x8*>(scr + (16 * tt + l15) * 64 + ((lh * 16) ^ swq));

  // ---- Phase 2: S^T = kn @ qn^T (lane: row m=tm*16+lh*4+r, col n=tn*16+l15) ----
  floatx4 sacc[4][4];
  #pragma unroll
  for (int tm = 0; tm < 4; ++tm)
    #pragma unroll
    for (int tn = 0; tn < 4; ++tn)
      sacc[tm][tn] = __builtin_amdgcn_mfma_f32_16x16x32_bf16(kf[tm], qf[tn], zf4, 0, 0, 0);

  // ---- Phase 3: +bias +mask, exp (bounded logits), col sums ----
  floatx4 rs;
  {
    const float* bh = biasT + h * 4096;
    const float* mw = mask + (size_t)(b & 255) * 4096;
    #pragma unroll
    for (int tn = 0; tn < 4; ++tn) {
      floatx4 bb[4], mm[4];
      #pragma unroll
      for (int tm = 0; tm < 4; ++tm) {
        int off = (tn * 16 + l15) * 64 + tm * 16 + lh * 4;
        bb[tm] = *reinterpret_cast<const floatx4*>(bh + off);
        mm[tm] = *reinterpret_cast<const floatx4*>(mw + off);
      }
      float sum = 0.f;
      #pragma unroll
      for (int tm = 0; tm < 4; ++tm) {
        float e0 = __expf(sacc[tm][tn][0] + bb[tm][0] + mm[tm][0]);
        float e1 = __expf(sacc[tm][tn][1] + bb[tm][1] + mm[tm][1]);
        float e2 = __expf(sacc[tm][tn][2] + bb[tm][2] + mm[tm][2]);
        float e3 = __expf(sacc[tm][tn][3] + bb[tm][3] + mm[tm][3]);
        sacc[tm][tn][0] = e0; sacc[tm][tn][1] = e1;
        sacc[tm][tn][2] = e2; sacc[tm][tn][3] = e3;
        sum += (e0 + e1) + (e2 + e3);
      }
      sum += __shfl_xor(sum, 16); sum += __shfl_xor(sum, 32);
      rs[tn] = 1.f / sum;
    }
  }

  // ---- Phase 4: O^T = V^T @ P^T, P in two 4KB half-transposes through scr ----
  floatx4 oacc[2][4];
  #pragma unroll
  for (int dt = 0; dt < 2; ++dt)
    #pragma unroll
    for (int nt = 0; nt < 4; ++nt) oacc[dt][nt] = zf4;
  #pragma unroll
  for (int k2 = 0; k2 < 2; ++k2) {
    // write P half: rows n (64 x 64B), cols m' = m - k2*32
    #pragma unroll
    for (int tn = 0; tn < 4; ++tn) {
      int rowb = (16 * tn + l15) * 64;
      #pragma unroll
      for (int t2 = 0; t2 < 2; ++t2) {
        floatx4 pv = sacc[k2 * 2 + t2][tn];
        uint2 w;
        w.x = pkbf(pv[0], pv[1]); w.y = pkbf(pv[2], pv[3]);
        *reinterpret_cast<uint2*>(scr + rowb + ((t2 * 32 + lh * 8) ^ swq)) = w;
      }
    }
    #pragma unroll
    for (int nt = 0; nt < 4; ++nt) {
      bf16x8 pf = *reinterpret_cast<const bf16x8*>(
          scr + (nt * 16 + l15) * 64 + ((lh * 16) ^ swq));
      #pragma unroll
      for (int dt = 0; dt < 2; ++dt)
        oacc[dt][nt] = __builtin_amdgcn_mfma_f32_16x16x32_bf16(vf[dt][k2], pf, oacc[dt][nt], 0, 0, 0);
    }
  }
  __syncthreads();   // all waves done with s_x (phase 1) before O overwrites it

  // O (scaled by 1/rowsum) -> s_x as [n][c] bf16, b64-packed writes
  #pragma unroll
  for (int dt = 0; dt < 2; ++dt) {
    #pragma unroll
    for (int nt = 0; nt < 4; ++nt) {
      int n = nt * 16 + l15;
      uint2 w;
      w.x = pkbf(oacc[dt][nt][0] * rs[nt], oacc[dt][nt][1] * rs[nt]);
      w.y = pkbf(oacc[dt][nt][2] * rs[nt], oacc[dt][nt][3] * rs[nt]);
      *reinterpret_cast<uint2*>(
          s_x + n * 256 + (((h * 32 + dt * 16 + lh * 4) * 2) ^ ((n & 7) << 4))) = w;
    }
  }
  __syncthreads();

  // ---- Phase 5: proj GEMM + bias, fp32 store ----
  floatx4 pacc[4][2];
  #pragma unroll
  for (int mt = 0; mt < 4; ++mt) { pacc[mt][0] = zf4; pacc[mt][1] = zf4; }
  #pragma unroll
  for (int kk = 0; kk < 4; ++kk) {
    bf16x8 of[4];
    #pragma unroll
    for (int mt = 0; mt < 4; ++mt) {
      int row = mt * 16 + l15;
      of[mt] = *reinterpret_cast<const bf16x8*>(
          s_x + row * 256 + (((kk * 32 + lh * 8) * 2) ^ ((row & 7) << 4)));
    }
    #pragma unroll
    for (int ft = 0; ft < 2; ++ft) {
      bf16x8 wp = *reinterpret_cast<const bf16x8*>(
          wproj + (size_t)(h * 32 + ft * 16 + l15) * 128 + kk * 32 + lh * 8);
      #pragma unroll
      for (int mt = 0; mt < 4; ++mt)
        pacc[mt][ft] = __builtin_amdgcn_mfma_f32_16x16x32_bf16(of[mt], wp, pacc[mt][ft], 0, 0, 0);
    }
  }
  {
    float pb0 = proj_b[h * 32 + l15], pb1 = proj_b[h * 32 + 16 + l15];
    float* ob = out + (size_t)b * 8192;
    #pragma unroll
    for (int mt = 0; mt < 4; ++mt)
      #pragma unroll
      for (int r = 0; r < 4; ++r) {
        int n = mt * 16 + lh * 4 + r;
        ob[n * 128 + h * 32 + l15]      = pacc[mt][0][r] + pb0;
        ob[n * 128 + h * 32 + 16 + l15] = pacc[mt][1][r] + pb1;
      }
  }
}

extern "C" void kernel_launch(void* const* d_in, const int* in_sizes, int n_in,
                              void* d_out, int out_size, void* d_ws, size_t ws_size,
                              hipStream_t stream)
{
  const float* x    = (const float*)d_in[0];
  const float* mask = (const float*)d_in[1];
  const float* qkvw = (const float*)d_in[2];
  const float* qb   = (const float*)d_in[3];
  const float* vb   = (const float*)d_in[4];
  const float* ls   = (const float*)d_in[5];
  const float* w1   = (const float*)d_in[6];
  const float* b1   = (const float*)d_in[7];
  const float* w2   = (const float*)d_in[8];
  const float* pw   = (const float*)d_in[9];
  const float* pb   = (const float*)d_in[10];
  float* out = (float*)d_out;
  char* ws = (char*)d_ws;

  unsigned short* wsQ = (unsigned short*)ws;   // qkv bf16 [0,49152) + proj bf16 [49152,65536)
  float* wsBias  = (float*)(ws + WS_BIAS);
  float* wsScale = (float*)(ws + WS_SCALE);
  float* wsTbl   = (float*)(ws + WS_TBL);

  hipLaunchKernelGGL(k_prep_weights, dim3(64), dim3(256), 0, stream, qkvw, pw, ls, wsQ, wsScale);
  hipLaunchKernelGGL(k_cpb_table, dim3(225), dim3(256), 0, stream, w1, b1, w2, wsTbl);
  hipLaunchKernelGGL(k_cpb_bias, dim3(64), dim3(256), 0, stream, wsTbl, wsBias);
  hipLaunchKernelGGL(k_wmsa, dim3(8192), dim3(256), 0, stream, x, mask,
                     wsQ, wsQ + 49152, qb, vb, wsBias, wsScale, pb, out);
}